// Round 10
// baseline (372.684 us; speedup 1.0000x reference)
//
#include <hip/hip_runtime.h>

#define CIN 128
#define CH 64
#define CO 40
#define BN_EPS 1e-5f
#define EPB 4096   // edges per pass1 block (16 per thread)
#define NT 4       // src tiles (src>>15)
#define GB 2048    // persistent gather blocks
#define NSLOT (GB * 4)
#define NPJ 13     // nodes per slot: NPJ*NSLOT >= N

typedef _Float16 h16;
typedef _Float16 f16x8 __attribute__((ext_vector_type(8)));
typedef float f32x4 __attribute__((ext_vector_type(4)));

// ---------- fused setup: edge dtype detect + zero gcnt/gcur + W1 prep ----------
__global__ void setup_kernel(const void* edge, int* flag,
                             int* __restrict__ gcnt, int* __restrict__ gcur,
                             const float* __restrict__ W1, h16* __restrict__ W1t) {
    __shared__ int bad;
    int t = threadIdx.x;
    if (t == 0) bad = 0;
    __syncthreads();
    if (t < 128) {
        int v = ((const int*)edge)[2 * t + 1];
        if (v != 0) bad = 1;
    }
    for (int i = t; i < 512; i += 256) { gcnt[i] = 0; gcur[i] = 0; }
    for (int i = t; i < 64 * 128; i += 256) {
        int c = i >> 7, k = i & 127;
        W1t[i] = (h16)W1[k * CH + c];
    }
    __syncthreads();
    if (t == 0) *flag = bad ? 0 : 1;   // 1 => int64
}

// ---------- pass1a: per-block LDS histogram of dst buckets ----------
__global__ __launch_bounds__(256) void pass1a_kernel(const void* edge, const int* __restrict__ flag,
                                                     int* __restrict__ gcnt, int E, int NB) {
    __shared__ int hist[512];
    int t = threadIdx.x;
    for (int i = t; i < NB; i += 256) hist[i] = 0;
    __syncthreads();
    int is64 = *flag;
    int base = blockIdx.x * EPB;
    if (is64) {
        const long long* dsts = (const long long*)edge + E;
#pragma unroll
        for (int i = 0; i < 8; ++i) {
            int e = base + i * 512 + t * 2;
            if (e + 1 < E) {
                int4 w = *(const int4*)(dsts + e);
                atomicAdd(&hist[w.x >> 8], 1);
                atomicAdd(&hist[w.z >> 8], 1);
            } else if (e < E) {
                atomicAdd(&hist[((int)dsts[e]) >> 8], 1);
            }
        }
    } else {
        const int* dsts = (const int*)edge + E;
#pragma unroll
        for (int i = 0; i < 8; ++i) {
            int e = base + i * 512 + t * 2;
            if (e + 1 < E) {
                int2 w = *(const int2*)(dsts + e);
                atomicAdd(&hist[w.x >> 8], 1);
                atomicAdd(&hist[w.y >> 8], 1);
            } else if (e < E) {
                atomicAdd(&hist[dsts[e] >> 8], 1);
            }
        }
    }
    __syncthreads();
    for (int i = t; i < NB; i += 256) if (hist[i]) atomicAdd(&gcnt[i], hist[i]);
}

// ---------- scanb: exclusive scan of bucket counts (NB <= 512) ----------
__global__ void scanb_kernel(const int* __restrict__ gcnt, int* __restrict__ gbase, int NB) {
    __shared__ int sm[512];
    int t = threadIdx.x;
    int v = (t < NB) ? gcnt[t] : 0;
    sm[t] = v;
    __syncthreads();
    for (int off = 1; off < 512; off <<= 1) {
        int u = (t >= off) ? sm[t - off] : 0;
        __syncthreads();
        sm[t] += u;
        __syncthreads();
    }
    if (t < NB) gbase[t] = sm[t] - v;
}

// ---------- pass1b: stage (src,dst) pairs bucket-contiguously ----------
__global__ __launch_bounds__(256) void pass1b_kernel(const void* edge, const int* __restrict__ flag,
                                                     const int* __restrict__ gbase, int* __restrict__ gcur,
                                                     int2* __restrict__ staging, int E, int NB) {
    __shared__ int hist[512];
    __shared__ int rbase[512];
    int t = threadIdx.x;
    for (int i = t; i < NB; i += 256) hist[i] = 0;
    __syncthreads();
    int is64 = *flag;
    int base = blockIdx.x * EPB;
    int2 ed[16];
    if (is64) {
        const long long* srcs = (const long long*)edge;
        const long long* dsts = srcs + E;
#pragma unroll
        for (int i = 0; i < 8; ++i) {
            int e = base + i * 512 + t * 2;
            int2 p0; p0.x = 0; p0.y = -1;
            int2 p1; p1.x = 0; p1.y = -1;
            if (e + 1 < E) {
                int4 sw = *(const int4*)(srcs + e);
                int4 dw = *(const int4*)(dsts + e);
                p0.x = sw.x; p0.y = dw.x;
                p1.x = sw.z; p1.y = dw.z;
                atomicAdd(&hist[p0.y >> 8], 1);
                atomicAdd(&hist[p1.y >> 8], 1);
            } else if (e < E) {
                p0.x = (int)srcs[e]; p0.y = (int)dsts[e];
                atomicAdd(&hist[p0.y >> 8], 1);
            }
            ed[i * 2] = p0; ed[i * 2 + 1] = p1;
        }
    } else {
        const int* srcs = (const int*)edge;
        const int* dsts = srcs + E;
#pragma unroll
        for (int i = 0; i < 8; ++i) {
            int e = base + i * 512 + t * 2;
            int2 p0; p0.x = 0; p0.y = -1;
            int2 p1; p1.x = 0; p1.y = -1;
            if (e + 1 < E) {
                int2 sw = *(const int2*)(srcs + e);
                int2 dw = *(const int2*)(dsts + e);
                p0.x = sw.x; p0.y = dw.x;
                p1.x = sw.y; p1.y = dw.y;
                atomicAdd(&hist[p0.y >> 8], 1);
                atomicAdd(&hist[p1.y >> 8], 1);
            } else if (e < E) {
                p0.x = srcs[e]; p0.y = dsts[e];
                atomicAdd(&hist[p0.y >> 8], 1);
            }
            ed[i * 2] = p0; ed[i * 2 + 1] = p1;
        }
    }
    __syncthreads();
    for (int i = t; i < NB; i += 256)
        rbase[i] = hist[i] ? gbase[i] + atomicAdd(&gcur[i], hist[i]) : 0;
    __syncthreads();
    for (int i = t; i < NB; i += 256) hist[i] = 0;   // reuse as local cursor
    __syncthreads();
#pragma unroll
    for (int i = 0; i < 16; ++i) {
        int2 p = ed[i];
        if (p.y >= 0) {
            int b = p.y >> 8;
            int pos = rbase[b] + atomicAdd(&hist[b], 1);
            staging[pos] = p;
        }
    }
}

// ---------- pass2f: per bucket — (node,tile) hist, scan -> rowptrT+dinv, tiled csr scatter ----------
__global__ __launch_bounds__(256) void pass2f_kernel(const int2* __restrict__ staging,
                                                     const int* __restrict__ gbase,
                                                     const int* __restrict__ gcnt,
                                                     int* __restrict__ rowptrT,
                                                     float* __restrict__ dinv,
                                                     int* __restrict__ csr, int N) {
    __shared__ int hist[256][NT];
    __shared__ int sm[256];
    __shared__ int cur[256][NT];
    int b = blockIdx.x, t = threadIdx.x;
#pragma unroll
    for (int q = 0; q < NT; ++q) hist[t][q] = 0;
    __syncthreads();
    int s0 = gbase[b], cnt = gcnt[b];
    for (int i = t; i < cnt; i += 256) {
        int2 p = staging[s0 + i];
        atomicAdd(&hist[p.y & 255][p.x >> 15], 1);
    }
    __syncthreads();
    int h0 = hist[t][0], h1 = hist[t][1], h2 = hist[t][2], h3 = hist[t][3];
    int v = h0 + h1 + h2 + h3;
    sm[t] = v;
    __syncthreads();
    for (int off = 1; off < 256; off <<= 1) {
        int u = (t >= off) ? sm[t - off] : 0;
        __syncthreads();
        sm[t] += u;
        __syncthreads();
    }
    int base = s0 + sm[t] - v;          // exclusive, absolute
    int n = b * 256 + t;
    if (n < N) {
        rowptrT[4 * n + 0] = base;
        rowptrT[4 * n + 1] = base + h0;
        rowptrT[4 * n + 2] = base + h0 + h1;
        rowptrT[4 * n + 3] = base + h0 + h1 + h2;
        cur[t][0] = base;
        cur[t][1] = base + h0;
        cur[t][2] = base + h0 + h1;
        cur[t][3] = base + h0 + h1 + h2;
        dinv[n] = rsqrtf((float)(v + 1));   // +1 self loop
    } else if (n == N) {
        rowptrT[4 * N] = base;              // == E in last bucket
    }
    __syncthreads();
    for (int i = t; i < cnt; i += 256) {
        int2 p = staging[s0 + i];
        int pos = atomicAdd(&cur[p.y & 255][p.x >> 15], 1);
        csr[pos] = p.x;
    }
}

// ---------- GEMM1 (MFMA f16) ----------
__global__ __launch_bounds__(256) void gemm1_kernel(const float* __restrict__ x,
                                                    const h16* __restrict__ W1t,
                                                    const float* __restrict__ dinv,
                                                    h16* __restrict__ buf1h, int N) {
    __shared__ h16 Ws[64 * 128];        // 16 KB, XOR-swizzled
    int t = threadIdx.x;
    for (int i = t; i < 64 * 16; i += 256) {
        int c = i >> 4, kc = (i & 15) * 8;
        unsigned byte = (unsigned)(c * 256 + kc * 2) ^ ((unsigned)(c & 7) << 4);
        *(f16x8*)&Ws[byte >> 1] = *(const f16x8*)&W1t[c * 128 + kc];
    }
    __syncthreads();
    int w = t >> 6, l = t & 63;
    int lm = l & 15, lk = l >> 4;
    int n0 = blockIdx.x * 64 + w * 16;
    const float* xrow = x + (long long)min(n0 + lm, N - 1) * CIN;
    f32x4 acc[4] = {};
#pragma unroll
    for (int ks = 0; ks < 4; ++ks) {
        int k0 = ks * 32 + lk * 8;
        float4 xa = *(const float4*)(xrow + k0);
        float4 xb = *(const float4*)(xrow + k0 + 4);
        f16x8 a;
        a[0] = (h16)xa.x; a[1] = (h16)xa.y; a[2] = (h16)xa.z; a[3] = (h16)xa.w;
        a[4] = (h16)xb.x; a[5] = (h16)xb.y; a[6] = (h16)xb.z; a[7] = (h16)xb.w;
#pragma unroll
        for (int ct = 0; ct < 4; ++ct) {
            int c = ct * 16 + lm;
            unsigned byte = (unsigned)(c * 256 + k0 * 2) ^ ((unsigned)(lm & 7) << 4);
            f16x8 b = *(const f16x8*)&Ws[byte >> 1];
            acc[ct] = __builtin_amdgcn_mfma_f32_16x16x32_f16(a, b, acc[ct], 0, 0, 0);
        }
    }
#pragma unroll
    for (int r = 0; r < 4; ++r) {
        int n = n0 + lk * 4 + r;
        if (n < N) {
            float dv = dinv[n];
#pragma unroll
            for (int ct = 0; ct < 4; ++ct)
                buf1h[n * CH + ct * 16 + lm] = (h16)(acc[ct][r] * dv);
        }
    }
}

// ---------- gather1 (persistent, src-tiled) + bias + BN + ReLU -> buf2 ----------
__global__ __launch_bounds__(256, 8) void gather1_kernel(const h16* __restrict__ buf1h,
                                                         const int* __restrict__ rowptrT,
                                                         const int* __restrict__ csr,
                                                         const float* __restrict__ dinv,
                                                         const float* __restrict__ b,
                                                         const float* __restrict__ g,
                                                         const float* __restrict__ be,
                                                         const float* __restrict__ m,
                                                         const float* __restrict__ v,
                                                         h16* __restrict__ buf2, int N) {
    int t = threadIdx.x;
    int r = t >> 6, c = t & 63;
    int slot = blockIdx.x * 4 + r;
    float P = g[c] * rsqrtf(v[c] + BN_EPS);
    float Q = (b[c] - m[c]) * P + be[c];
    float acc[NPJ];
#pragma unroll
    for (int j = 0; j < NPJ; ++j) {
        int n = slot + j * NSLOT;
        acc[j] = (n < N) ? (float)buf1h[(long long)n * CH + c] : 0.0f;   // self loop
    }
    for (int tile = 0; tile < NT; ++tile) {
#pragma unroll
        for (int j = 0; j < NPJ; ++j) {
            int n = slot + j * NSLOT;
            if (n >= N) continue;
            int k0 = rowptrT[4 * n + tile];
            int k1 = (tile == NT - 1) ? rowptrT[4 * n + 4] : rowptrT[4 * n + tile + 1];
            for (int k = k0; k < k1; k += 64) {
                int cnt = min(64, k1 - k);
                int sv = (c < cnt) ? csr[k + c] : 0;
                int jj = 0;
                for (; jj + 4 <= cnt; jj += 4) {
                    int s0 = __shfl(sv, jj),     s1 = __shfl(sv, jj + 1);
                    int s2 = __shfl(sv, jj + 2), s3 = __shfl(sv, jj + 3);
                    float a0 = (float)buf1h[(long long)s0 * CH + c];
                    float a1 = (float)buf1h[(long long)s1 * CH + c];
                    float a2 = (float)buf1h[(long long)s2 * CH + c];
                    float a3 = (float)buf1h[(long long)s3 * CH + c];
                    acc[j] += a0; acc[j] += a1; acc[j] += a2; acc[j] += a3;
                }
                for (; jj < cnt; ++jj) {
                    int s = __shfl(sv, jj);
                    acc[j] += (float)buf1h[(long long)s * CH + c];
                }
            }
        }
    }
#pragma unroll
    for (int j = 0; j < NPJ; ++j) {
        int n = slot + j * NSLOT;
        if (n < N) {
            float dv = dinv[n];
            buf2[(long long)n * CH + c] = (h16)fmaxf(dv * acc[j] * P + Q, 0.0f);
        }
    }
}

// ---------- GEMM2 (MFMA f16): hs2h packed stride CO=40 ----------
__global__ __launch_bounds__(256) void gemm2_kernel(const h16* __restrict__ x2,
                                                    const float* __restrict__ W2,
                                                    const float* __restrict__ dinv,
                                                    h16* __restrict__ hs2h, int N) {
    __shared__ h16 Ws[48 * 64];         // 6 KB, XOR-swizzled (transposed in-kernel)
    int t = threadIdx.x;
    for (int i = t; i < 48 * 64; i += 256) {
        int cc = i >> 6, k = i & 63;
        h16 w = (h16)((cc < CO) ? W2[k * CO + cc] : 0.0f);
        unsigned byte = (unsigned)(cc * 128 + k * 2) ^ ((unsigned)(cc & 7) << 4);
        Ws[byte >> 1] = w;
    }
    __syncthreads();
    int w = t >> 6, l = t & 63;
    int lm = l & 15, lk = l >> 4;
    int n0 = blockIdx.x * 64 + w * 16;
    const h16* xrow = x2 + (long long)min(n0 + lm, N - 1) * CH;
    f32x4 acc[3] = {};
#pragma unroll
    for (int ks = 0; ks < 2; ++ks) {
        int k0 = ks * 32 + lk * 8;
        f16x8 a = *(const f16x8*)(xrow + k0);
#pragma unroll
        for (int ct = 0; ct < 3; ++ct) {
            int cc = ct * 16 + lm;
            unsigned byte = (unsigned)(cc * 128 + k0 * 2) ^ ((unsigned)(lm & 7) << 4);
            f16x8 bb = *(const f16x8*)&Ws[byte >> 1];
            acc[ct] = __builtin_amdgcn_mfma_f32_16x16x32_f16(a, bb, acc[ct], 0, 0, 0);
        }
    }
#pragma unroll
    for (int r = 0; r < 4; ++r) {
        int n = n0 + lk * 4 + r;
        if (n < N) {
            float dv = dinv[n];
#pragma unroll
            for (int ct = 0; ct < 3; ++ct) {
                int cc = ct * 16 + lm;
                if (cc < CO) hs2h[(long long)n * CO + cc] = (h16)(acc[ct][r] * dv);
            }
        }
    }
}

// ---------- gather2 (persistent, src-tiled) + bias + BN + ReLU -> out ----------
__global__ __launch_bounds__(256, 8) void gather2_kernel(const h16* __restrict__ hs2h,
                                                         const int* __restrict__ rowptrT,
                                                         const int* __restrict__ csr,
                                                         const float* __restrict__ dinv,
                                                         const float* __restrict__ b,
                                                         const float* __restrict__ g,
                                                         const float* __restrict__ be,
                                                         const float* __restrict__ m,
                                                         const float* __restrict__ v,
                                                         float* __restrict__ out, int N) {
    int t = threadIdx.x;
    int r = t >> 6, c = t & 63;
    int slot = blockIdx.x * 4 + r;
    bool cok = (c < CO);
    float P = 0.0f, Q = 0.0f;
    if (cok) {
        P = g[c] * rsqrtf(v[c] + BN_EPS);
        Q = (b[c] - m[c]) * P + be[c];
    }
    float acc[NPJ];
#pragma unroll
    for (int j = 0; j < NPJ; ++j) {
        int n = slot + j * NSLOT;
        acc[j] = (cok && n < N) ? (float)hs2h[(long long)n * CO + c] : 0.0f;   // self loop
    }
    for (int tile = 0; tile < NT; ++tile) {
#pragma unroll
        for (int j = 0; j < NPJ; ++j) {
            int n = slot + j * NSLOT;
            if (n >= N) continue;
            int k0 = rowptrT[4 * n + tile];
            int k1 = (tile == NT - 1) ? rowptrT[4 * n + 4] : rowptrT[4 * n + tile + 1];
            for (int k = k0; k < k1; k += 64) {
                int cnt = min(64, k1 - k);
                int sv = (c < cnt) ? csr[k + c] : 0;
                int jj = 0;
                for (; jj + 4 <= cnt; jj += 4) {
                    int s0 = __shfl(sv, jj),     s1 = __shfl(sv, jj + 1);
                    int s2 = __shfl(sv, jj + 2), s3 = __shfl(sv, jj + 3);
                    float a0 = cok ? (float)hs2h[(long long)s0 * CO + c] : 0.0f;
                    float a1 = cok ? (float)hs2h[(long long)s1 * CO + c] : 0.0f;
                    float a2 = cok ? (float)hs2h[(long long)s2 * CO + c] : 0.0f;
                    float a3 = cok ? (float)hs2h[(long long)s3 * CO + c] : 0.0f;
                    acc[j] += a0; acc[j] += a1; acc[j] += a2; acc[j] += a3;
                }
                for (; jj < cnt; ++jj) {
                    int s = __shfl(sv, jj);
                    if (cok) acc[j] += (float)hs2h[(long long)s * CO + c];
                }
            }
        }
    }
#pragma unroll
    for (int j = 0; j < NPJ; ++j) {
        int n = slot + j * NSLOT;
        if (cok && n < N) {
            float dv = dinv[n];
            out[(long long)n * CO + c] = fmaxf(dv * acc[j] * P + Q, 0.0f);
        }
    }
}

extern "C" void kernel_launch(void* const* d_in, const int* in_sizes, int n_in,
                              void* d_out, int out_size, void* d_ws, size_t ws_size,
                              hipStream_t stream) {
    const float* x    = (const float*)d_in[0];
    const void*  edge = d_in[1];
    const float* W1  = (const float*)d_in[2];
    const float* b1  = (const float*)d_in[3];
    const float* g1  = (const float*)d_in[4];
    const float* be1 = (const float*)d_in[5];
    const float* m1  = (const float*)d_in[6];
    const float* v1  = (const float*)d_in[7];
    const float* W2  = (const float*)d_in[8];
    const float* b2  = (const float*)d_in[9];
    const float* g2  = (const float*)d_in[10];
    const float* be2 = (const float*)d_in[11];
    const float* m2  = (const float*)d_in[12];
    const float* v2  = (const float*)d_in[13];

    const int N  = in_sizes[0] / CIN;       // 100000
    const int E  = in_sizes[1] / 2;         // 1600000
    const int NB = (N + 255) / 256;         // 391 buckets
    const int nblk1 = (E + EPB - 1) / EPB;
    const int nb64 = (N + 63) / 64;

    // workspace layout (4-byte units; staging 16B-aligned)
    float* ws     = (float*)d_ws;
    size_t off = 0;
    float* dinv    = ws + off;                  off += N;
    int*   rowptrT = (int*)(ws + off);          off += 4 * N + 4;
    int*   gcnt    = (int*)(ws + off);          off += 512;
    int*   gbase   = (int*)(ws + off);          off += 512;
    int*   gcur    = (int*)(ws + off);          off += 512;
    off = (off + 3) & ~(size_t)3;
    int2*  staging = (int2*)(ws + off);         off += (size_t)2 * E;
    int*   csr     = (int*)(ws + off);          off += E;
    h16*   W1t     = (h16*)(ws + off);          off += 64 * 128 / 2;
    off = (off + 3) & ~(size_t)3;
    h16*   buf1h   = (h16*)(ws + off);          off += (size_t)(CH / 2) * N + 4;
    off = (off + 3) & ~(size_t)3;
    h16*   buf2    = (h16*)(ws + off);          off += (size_t)(CH / 2) * N + 4;
    off = (off + 3) & ~(size_t)3;
    h16*   hs2h    = (h16*)(ws + off);          off += (size_t)(CO / 2) * N + 4;
    int*   flag    = (int*)(ws + off);

    float* out = (float*)d_out;

    setup_kernel<<<1, 256, 0, stream>>>(edge, flag, gcnt, gcur, W1, W1t);
    pass1a_kernel<<<nblk1, 256, 0, stream>>>(edge, flag, gcnt, E, NB);
    scanb_kernel<<<1, 512, 0, stream>>>(gcnt, gbase, NB);
    pass1b_kernel<<<nblk1, 256, 0, stream>>>(edge, flag, gbase, gcur, staging, E, NB);
    pass2f_kernel<<<NB, 256, 0, stream>>>(staging, gbase, gcnt, rowptrT, dinv, csr, N);
    gemm1_kernel<<<nb64, 256, 0, stream>>>(x, W1t, dinv, buf1h, N);
    gather1_kernel<<<GB, 256, 0, stream>>>(buf1h, rowptrT, csr, dinv, b1, g1, be1, m1, v1, buf2, N);
    gemm2_kernel<<<nb64, 256, 0, stream>>>(buf2, W2, dinv, hs2h, N);
    gather2_kernel<<<GB, 256, 0, stream>>>(hs2h, rowptrT, csr, dinv, b2, g2, be2, m2, v2, out, N);
}

// Round 11
// 246.494 us; speedup vs baseline: 1.5119x; 1.5119x over previous
//
#include <hip/hip_runtime.h>

#define CIN 128
#define CH 64
#define CO 40
#define BN_EPS 1e-5f
#define EPB 4096   // edges per pass1 block (16 per thread)

typedef _Float16 h16;
typedef _Float16 f16x8 __attribute__((ext_vector_type(8)));
typedef float f32x4 __attribute__((ext_vector_type(4)));

// ---------- fused setup: edge dtype detect + zero gcnt/gcur + W prep ----------
__global__ void setup_kernel(const void* edge, int* flag,
                             int* __restrict__ gcnt, int* __restrict__ gcur,
                             const float* __restrict__ W1, const float* __restrict__ W2,
                             h16* __restrict__ W1t, h16* __restrict__ W2t) {
    __shared__ int bad;
    int t = threadIdx.x;
    if (t == 0) bad = 0;
    __syncthreads();
    if (t < 128) {
        int v = ((const int*)edge)[2 * t + 1];
        if (v != 0) bad = 1;
    }
    for (int i = t; i < 512; i += 256) { gcnt[i] = 0; gcur[i] = 0; }
    for (int i = t; i < 64 * 128; i += 256) {
        int c = i >> 7, k = i & 127;
        W1t[i] = (h16)W1[k * CH + c];
    }
    for (int i = t; i < 48 * 64; i += 256) {
        int c = i >> 6, k = i & 63;
        W2t[i] = (h16)((c < CO) ? W2[k * CO + c] : 0.0f);
    }
    __syncthreads();
    if (t == 0) *flag = bad ? 0 : 1;   // 1 => int64
}

// ---------- pass1a: per-block LDS histogram of dst buckets (vectorized reads) ----------
__global__ __launch_bounds__(256) void pass1a_kernel(const void* edge, const int* __restrict__ flag,
                                                     int* __restrict__ gcnt, int E, int NB) {
    __shared__ int hist[512];
    int t = threadIdx.x;
    for (int i = t; i < NB; i += 256) hist[i] = 0;
    __syncthreads();
    int is64 = *flag;
    int base = blockIdx.x * EPB;
    if (is64) {
        const long long* dsts = (const long long*)edge + E;
#pragma unroll
        for (int i = 0; i < 8; ++i) {
            int e = base + i * 512 + t * 2;
            if (e + 1 < E) {
                int4 w = *(const int4*)(dsts + e);      // two int64; low dwords .x,.z
                atomicAdd(&hist[w.x >> 8], 1);
                atomicAdd(&hist[w.z >> 8], 1);
            } else if (e < E) {
                atomicAdd(&hist[((int)dsts[e]) >> 8], 1);
            }
        }
    } else {
        const int* dsts = (const int*)edge + E;
#pragma unroll
        for (int i = 0; i < 8; ++i) {
            int e = base + i * 512 + t * 2;
            if (e + 1 < E) {
                int2 w = *(const int2*)(dsts + e);
                atomicAdd(&hist[w.x >> 8], 1);
                atomicAdd(&hist[w.y >> 8], 1);
            } else if (e < E) {
                atomicAdd(&hist[dsts[e] >> 8], 1);
            }
        }
    }
    __syncthreads();
    for (int i = t; i < NB; i += 256) if (hist[i]) atomicAdd(&gcnt[i], hist[i]);
}

// ---------- scanb: exclusive scan of bucket counts (NB <= 512) ----------
__global__ void scanb_kernel(const int* __restrict__ gcnt, int* __restrict__ gbase, int NB) {
    __shared__ int sm[512];
    int t = threadIdx.x;
    int v = (t < NB) ? gcnt[t] : 0;
    sm[t] = v;
    __syncthreads();
    for (int off = 1; off < 512; off <<= 1) {
        int u = (t >= off) ? sm[t - off] : 0;
        __syncthreads();
        sm[t] += u;
        __syncthreads();
    }
    if (t < NB) gbase[t] = sm[t] - v;
}

// ---------- pass1b: stage (src,dst) pairs bucket-contiguously (vectorized reads) ----------
__global__ __launch_bounds__(256) void pass1b_kernel(const void* edge, const int* __restrict__ flag,
                                                     const int* __restrict__ gbase, int* __restrict__ gcur,
                                                     int2* __restrict__ staging, int E, int NB) {
    __shared__ int hist[512];
    __shared__ int rbase[512];
    int t = threadIdx.x;
    for (int i = t; i < NB; i += 256) hist[i] = 0;
    __syncthreads();
    int is64 = *flag;
    int base = blockIdx.x * EPB;
    int2 ed[16];
    if (is64) {
        const long long* srcs = (const long long*)edge;
        const long long* dsts = srcs + E;
#pragma unroll
        for (int i = 0; i < 8; ++i) {
            int e = base + i * 512 + t * 2;
            int2 p0; p0.x = 0; p0.y = -1;
            int2 p1; p1.x = 0; p1.y = -1;
            if (e + 1 < E) {
                int4 sw = *(const int4*)(srcs + e);
                int4 dw = *(const int4*)(dsts + e);
                p0.x = sw.x; p0.y = dw.x;
                p1.x = sw.z; p1.y = dw.z;
                atomicAdd(&hist[p0.y >> 8], 1);
                atomicAdd(&hist[p1.y >> 8], 1);
            } else if (e < E) {
                p0.x = (int)srcs[e]; p0.y = (int)dsts[e];
                atomicAdd(&hist[p0.y >> 8], 1);
            }
            ed[i * 2] = p0; ed[i * 2 + 1] = p1;
        }
    } else {
        const int* srcs = (const int*)edge;
        const int* dsts = srcs + E;
#pragma unroll
        for (int i = 0; i < 8; ++i) {
            int e = base + i * 512 + t * 2;
            int2 p0; p0.x = 0; p0.y = -1;
            int2 p1; p1.x = 0; p1.y = -1;
            if (e + 1 < E) {
                int2 sw = *(const int2*)(srcs + e);
                int2 dw = *(const int2*)(dsts + e);
                p0.x = sw.x; p0.y = dw.x;
                p1.x = sw.y; p1.y = dw.y;
                atomicAdd(&hist[p0.y >> 8], 1);
                atomicAdd(&hist[p1.y >> 8], 1);
            } else if (e < E) {
                p0.x = srcs[e]; p0.y = dsts[e];
                atomicAdd(&hist[p0.y >> 8], 1);
            }
            ed[i * 2] = p0; ed[i * 2 + 1] = p1;
        }
    }
    __syncthreads();
    for (int i = t; i < NB; i += 256)
        rbase[i] = hist[i] ? gbase[i] + atomicAdd(&gcur[i], hist[i]) : 0;
    __syncthreads();
    for (int i = t; i < NB; i += 256) hist[i] = 0;   // reuse as local cursor
    __syncthreads();
#pragma unroll
    for (int i = 0; i < 16; ++i) {
        int2 p = ed[i];
        if (p.y >= 0) {
            int b = p.y >> 8;
            int pos = rbase[b] + atomicAdd(&hist[b], 1);
            staging[pos] = p;
        }
    }
}

// ---------- pass2f: per bucket — deg hist, local scan -> rowptr+dinv, csr scatter ----------
__global__ __launch_bounds__(256) void pass2f_kernel(const int2* __restrict__ staging,
                                                     const int* __restrict__ gbase,
                                                     const int* __restrict__ gcnt,
                                                     int* __restrict__ rowptr,
                                                     float* __restrict__ dinv,
                                                     int* __restrict__ csr, int N) {
    __shared__ int hist[256];
    __shared__ int scan[256];
    __shared__ int cur[256];
    int b = blockIdx.x, t = threadIdx.x;
    hist[t] = 0;
    __syncthreads();
    int s0 = gbase[b], cnt = gcnt[b];
    for (int i = t; i < cnt; i += 256) {
        int d = staging[s0 + i].y;
        atomicAdd(&hist[d & 255], 1);
    }
    __syncthreads();
    int v = hist[t];
    scan[t] = v;
    __syncthreads();
    for (int off = 1; off < 256; off <<= 1) {
        int u = (t >= off) ? scan[t - off] : 0;
        __syncthreads();
        scan[t] += u;
        __syncthreads();
    }
    int ex = scan[t] - v;               // exclusive
    cur[t] = ex;
    int n = b * 256 + t;
    if (n <= N) rowptr[n] = s0 + ex;
    if (n < N)  dinv[n]   = rsqrtf((float)(v + 1));   // +1 self loop
    __syncthreads();
    for (int i = t; i < cnt; i += 256) {
        int2 p = staging[s0 + i];
        int pos = atomicAdd(&cur[p.y & 255], 1);
        csr[s0 + pos] = p.x;
    }
}

// ---------- GEMM1 (MFMA f16) ----------
__global__ __launch_bounds__(256) void gemm1_kernel(const float* __restrict__ x,
                                                    const h16* __restrict__ W1t,
                                                    const float* __restrict__ dinv,
                                                    h16* __restrict__ buf1h, int N) {
    __shared__ h16 Ws[64 * 128];        // 16 KB, XOR-swizzled
    int t = threadIdx.x;
    for (int i = t; i < 64 * 16; i += 256) {
        int c = i >> 4, kc = (i & 15) * 8;
        unsigned byte = (unsigned)(c * 256 + kc * 2) ^ ((unsigned)(c & 7) << 4);
        *(f16x8*)&Ws[byte >> 1] = *(const f16x8*)&W1t[c * 128 + kc];
    }
    __syncthreads();
    int w = t >> 6, l = t & 63;
    int lm = l & 15, lk = l >> 4;
    int n0 = blockIdx.x * 64 + w * 16;
    const float* xrow = x + (long long)min(n0 + lm, N - 1) * CIN;
    f32x4 acc[4] = {};
#pragma unroll
    for (int ks = 0; ks < 4; ++ks) {
        int k0 = ks * 32 + lk * 8;
        float4 xa = *(const float4*)(xrow + k0);
        float4 xb = *(const float4*)(xrow + k0 + 4);
        f16x8 a;
        a[0] = (h16)xa.x; a[1] = (h16)xa.y; a[2] = (h16)xa.z; a[3] = (h16)xa.w;
        a[4] = (h16)xb.x; a[5] = (h16)xb.y; a[6] = (h16)xb.z; a[7] = (h16)xb.w;
#pragma unroll
        for (int ct = 0; ct < 4; ++ct) {
            int c = ct * 16 + lm;
            unsigned byte = (unsigned)(c * 256 + k0 * 2) ^ ((unsigned)(lm & 7) << 4);
            f16x8 b = *(const f16x8*)&Ws[byte >> 1];
            acc[ct] = __builtin_amdgcn_mfma_f32_16x16x32_f16(a, b, acc[ct], 0, 0, 0);
        }
    }
#pragma unroll
    for (int r = 0; r < 4; ++r) {
        int n = n0 + lk * 4 + r;
        if (n < N) {
            float dv = dinv[n];
#pragma unroll
            for (int ct = 0; ct < 4; ++ct)
                buf1h[n * CH + ct * 16 + lm] = (h16)(acc[ct][r] * dv);
        }
    }
}

// ---------- gather1 + bias + BN + ReLU -> buf2 (f16), unroll-8 ----------
__global__ __launch_bounds__(256) void gather1_kernel(const h16* __restrict__ buf1h,
                                                      const int* __restrict__ rowptr,
                                                      const int* __restrict__ csr,
                                                      const float* __restrict__ dinv,
                                                      const float* __restrict__ b,
                                                      const float* __restrict__ g,
                                                      const float* __restrict__ be,
                                                      const float* __restrict__ m,
                                                      const float* __restrict__ v,
                                                      h16* __restrict__ buf2, int N) {
    int t = threadIdx.x;
    int r = t >> 6, c = t & 63;
    int n = blockIdx.x * 4 + r;
    if (n >= N) return;
    int start = rowptr[n], end = rowptr[n + 1];
    float acc = (float)buf1h[n * CH + c];   // self loop
    for (int k = start; k < end; k += 64) {
        int cnt = min(64, end - k);
        int sv = (c < cnt) ? csr[k + c] : 0;
        int j = 0;
        for (; j + 8 <= cnt; j += 8) {
            int s[8];
#pragma unroll
            for (int u = 0; u < 8; ++u) s[u] = __shfl(sv, j + u);
            float a[8];
#pragma unroll
            for (int u = 0; u < 8; ++u) a[u] = (float)buf1h[s[u] * CH + c];
#pragma unroll
            for (int u = 0; u < 8; ++u) acc += a[u];
        }
        for (; j < cnt; ++j) {
            int s0 = __shfl(sv, j);
            acc += (float)buf1h[s0 * CH + c];
        }
    }
    float z = dinv[n] * acc + b[c];
    float y = (z - m[c]) * rsqrtf(v[c] + BN_EPS) * g[c] + be[c];
    buf2[n * CH + c] = (h16)fmaxf(y, 0.0f);
}

// ---------- GEMM2 (MFMA f16): split output bufA [N][32] + bufB [N][8] ----------
__global__ __launch_bounds__(256) void gemm2_kernel(const h16* __restrict__ x2,
                                                    const h16* __restrict__ W2t,
                                                    const float* __restrict__ dinv,
                                                    h16* __restrict__ bufA,
                                                    h16* __restrict__ bufB, int N) {
    __shared__ h16 Ws[48 * 64];         // 6 KB, XOR-swizzled
    int t = threadIdx.x;
    for (int i = t; i < 48 * 8; i += 256) {
        int c = i >> 3, kc = (i & 7) * 8;
        unsigned byte = (unsigned)(c * 128 + kc * 2) ^ ((unsigned)(c & 7) << 4);
        *(f16x8*)&Ws[byte >> 1] = *(const f16x8*)&W2t[c * 64 + kc];
    }
    __syncthreads();
    int w = t >> 6, l = t & 63;
    int lm = l & 15, lk = l >> 4;
    int n0 = blockIdx.x * 64 + w * 16;
    const h16* xrow = x2 + (long long)min(n0 + lm, N - 1) * CH;
    f32x4 acc[3] = {};
#pragma unroll
    for (int ks = 0; ks < 2; ++ks) {
        int k0 = ks * 32 + lk * 8;
        f16x8 a = *(const f16x8*)(xrow + k0);
#pragma unroll
        for (int ct = 0; ct < 3; ++ct) {
            int c = ct * 16 + lm;
            unsigned byte = (unsigned)(c * 128 + k0 * 2) ^ ((unsigned)(lm & 7) << 4);
            f16x8 b = *(const f16x8*)&Ws[byte >> 1];
            acc[ct] = __builtin_amdgcn_mfma_f32_16x16x32_f16(a, b, acc[ct], 0, 0, 0);
        }
    }
#pragma unroll
    for (int r = 0; r < 4; ++r) {
        int n = n0 + lk * 4 + r;
        if (n < N) {
            float dv = dinv[n];
#pragma unroll
            for (int ct = 0; ct < 2; ++ct)      // channels 0..31 -> bufA
                bufA[(long long)n * 32 + ct * 16 + lm] = (h16)(acc[ct][r] * dv);
            if (lm < 8)                          // channels 32..39 -> bufB
                bufB[(long long)n * 8 + lm] = (h16)(acc[2][r] * dv);
        }
    }
}

// ---------- gather2 (split src) + bias + BN + ReLU -> out, unroll-8 ----------
__global__ __launch_bounds__(256) void gather2_kernel(const h16* __restrict__ bufA,
                                                      const h16* __restrict__ bufB,
                                                      const int* __restrict__ rowptr,
                                                      const int* __restrict__ csr,
                                                      const float* __restrict__ dinv,
                                                      const float* __restrict__ b,
                                                      const float* __restrict__ g,
                                                      const float* __restrict__ be,
                                                      const float* __restrict__ m,
                                                      const float* __restrict__ v,
                                                      float* __restrict__ out, int N) {
    int t = threadIdx.x;
    int r = t >> 6, c = t & 63;
    int n = blockIdx.x * 4 + r;
    if (n >= N) return;
    bool inA = (c < 32);
    bool inB = (c >= 32) && (c < CO);
    // per-lane source pointer: lanes 0..31 stride-32 (64B rows), 32..39 stride-8 (16B rows)
    const h16* src = inA ? (bufA + c) : (inB ? (bufB + (c - 32)) : bufA);
    int stride = inA ? 32 : 8;
    int start = rowptr[n], end = rowptr[n + 1];
    float acc = (c < CO) ? (float)src[(long long)n * stride] : 0.0f;   // self loop
    for (int k = start; k < end; k += 64) {
        int cnt = min(64, end - k);
        int sv = (c < cnt) ? csr[k + c] : 0;
        int j = 0;
        for (; j + 8 <= cnt; j += 8) {
            int s[8];
#pragma unroll
            for (int u = 0; u < 8; ++u) s[u] = __shfl(sv, j + u);
            float a[8];
#pragma unroll
            for (int u = 0; u < 8; ++u)
                a[u] = (c < CO) ? (float)src[(long long)s[u] * stride] : 0.0f;
#pragma unroll
            for (int u = 0; u < 8; ++u) acc += a[u];
        }
        for (; j < cnt; ++j) {
            int s0 = __shfl(sv, j);
            if (c < CO) acc += (float)src[(long long)s0 * stride];
        }
    }
    if (c < CO) {
        float z = dinv[n] * acc + b[c];
        float y = (z - m[c]) * rsqrtf(v[c] + BN_EPS) * g[c] + be[c];
        out[(long long)n * CO + c] = fmaxf(y, 0.0f);
    }
}

extern "C" void kernel_launch(void* const* d_in, const int* in_sizes, int n_in,
                              void* d_out, int out_size, void* d_ws, size_t ws_size,
                              hipStream_t stream) {
    const float* x    = (const float*)d_in[0];
    const void*  edge = d_in[1];
    const float* W1  = (const float*)d_in[2];
    const float* b1  = (const float*)d_in[3];
    const float* g1  = (const float*)d_in[4];
    const float* be1 = (const float*)d_in[5];
    const float* m1  = (const float*)d_in[6];
    const float* v1  = (const float*)d_in[7];
    const float* W2  = (const float*)d_in[8];
    const float* b2  = (const float*)d_in[9];
    const float* g2  = (const float*)d_in[10];
    const float* be2 = (const float*)d_in[11];
    const float* m2  = (const float*)d_in[12];
    const float* v2  = (const float*)d_in[13];

    const int N  = in_sizes[0] / CIN;       // 100000
    const int E  = in_sizes[1] / 2;         // 1600000
    const int NB = (N + 255) / 256;         // 391 buckets
    const int nblk1 = (E + EPB - 1) / EPB;
    const int nb64 = (N + 63) / 64;

    // workspace layout (4-byte units; 16B-align the h16 buffers)
    float* ws     = (float*)d_ws;
    size_t off = 0;
    float* dinv   = ws + off;                   off += N;
    int*   rowptr = (int*)(ws + off);           off += N + 2;
    int*   gcnt   = (int*)(ws + off);           off += 512;
    int*   gbase  = (int*)(ws + off);           off += 512;
    int*   gcur   = (int*)(ws + off);           off += 512;
    off = (off + 3) & ~(size_t)3;
    int2*  staging = (int2*)(ws + off);         off += (size_t)2 * E;
    int*   csr    = (int*)(ws + off);           off += E;
    h16*   W1t    = (h16*)(ws + off);           off += 64 * 128 / 2;
    h16*   W2t    = (h16*)(ws + off);           off += 48 * 64 / 2;
    off = (off + 3) & ~(size_t)3;
    h16*   buf1h  = (h16*)(ws + off);           off += (size_t)(CH / 2) * N + 4;
    off = (off + 3) & ~(size_t)3;
    h16*   buf2   = (h16*)(ws + off);           off += (size_t)(CH / 2) * N + 4;
    off = (off + 3) & ~(size_t)3;
    h16*   bufA   = (h16*)(ws + off);           off += (size_t)16 * N + 4;   // [N][32] h16
    off = (off + 3) & ~(size_t)3;
    h16*   bufB   = (h16*)(ws + off);           off += (size_t)4 * N + 4;    // [N][8] h16
    int*   flag   = (int*)(ws + off);

    float* out = (float*)d_out;

    setup_kernel<<<1, 256, 0, stream>>>(edge, flag, gcnt, gcur, W1, W2, W1t, W2t);
    pass1a_kernel<<<nblk1, 256, 0, stream>>>(edge, flag, gcnt, E, NB);
    scanb_kernel<<<1, 512, 0, stream>>>(gcnt, gbase, NB);
    pass1b_kernel<<<nblk1, 256, 0, stream>>>(edge, flag, gbase, gcur, staging, E, NB);
    pass2f_kernel<<<NB, 256, 0, stream>>>(staging, gbase, gcnt, rowptr, dinv, csr, N);
    gemm1_kernel<<<nb64, 256, 0, stream>>>(x, W1t, dinv, buf1h, N);
    gather1_kernel<<<(N + 3) / 4, 256, 0, stream>>>(buf1h, rowptr, csr, dinv, b1, g1, be1, m1, v1, buf2, N);
    gemm2_kernel<<<nb64, 256, 0, stream>>>(buf2, W2t, dinv, bufA, bufB, N);
    gather2_kernel<<<(N + 3) / 4, 256, 0, stream>>>(bufA, bufB, rowptr, csr, dinv, b2, g2, be2, m2, v2, out, N);
}